// Round 5
// baseline (603.221 us; speedup 1.0000x reference)
//
#include <hip/hip_runtime.h>
#include <hip/hip_bf16.h>

#define N_ 8192
#define F_ 256
#define H_ 128
#define L_ 32

typedef __attribute__((ext_vector_type(8))) short bf16x8;
typedef __attribute__((ext_vector_type(4))) float f32x4;
typedef __attribute__((ext_vector_type(4))) short bf16x4;

// RNE float -> bf16 (finite inputs only)
__device__ __forceinline__ unsigned f2bf_u(float x) {
    unsigned u = __builtin_bit_cast(unsigned, x);
    return (u + 0x7fffu + ((u >> 16) & 1u)) >> 16;
}
__device__ __forceinline__ short f2bf(float x) { return (short)f2bf_u(x); }

__device__ __forceinline__ bf16x8 cvt8(float4 a, float4 b) {
    bf16x8 v;
    v[0] = f2bf(a.x); v[1] = f2bf(a.y); v[2] = f2bf(a.z); v[3] = f2bf(a.w);
    v[4] = f2bf(b.x); v[5] = f2bf(b.y); v[6] = f2bf(b.z); v[7] = f2bf(b.w);
    return v;
}

// ---------------------------------------------------------------------------
// k1: XW1T[n][i] = (X @ W1)[i][n], bf16.  64 rows/block, 4 waves x 16 rows.
// ---------------------------------------------------------------------------
__global__ __launch_bounds__(256) void k1_xw1(const float* __restrict__ X,
                                              const float* __restrict__ W1,
                                              short* __restrict__ XW1T) {
    __shared__ short w1t[H_ * (F_ + 8)];
    const int tid = threadIdx.x;
    for (int idx = tid; idx < F_ * H_; idx += 256) {
        int k = idx >> 7, n = idx & 127;
        w1t[n * (F_ + 8) + k] = f2bf(W1[idx]);
    }
    __syncthreads();
    const int wv = tid >> 6, l = tid & 63;
    const int lm = l & 15, q = l >> 4;
    const int i0 = blockIdx.x * 64 + wv * 16;
    const float* xrow = X + (size_t)(i0 + lm) * F_;
    f32x4 acc[8];
#pragma unroll
    for (int j = 0; j < 8; ++j) acc[j] = (f32x4){0.f, 0.f, 0.f, 0.f};
#pragma unroll
    for (int k0 = 0; k0 < F_; k0 += 32) {
        float4 a0 = *(const float4*)(xrow + k0 + q * 8);
        float4 a1 = *(const float4*)(xrow + k0 + q * 8 + 4);
        bf16x8 af = cvt8(a0, a1);
#pragma unroll
        for (int j = 0; j < 8; ++j) {
            bf16x8 bf = *(const bf16x8*)&w1t[(j * 16 + lm) * (F_ + 8) + k0 + q * 8];
            acc[j] = __builtin_amdgcn_mfma_f32_16x16x32_bf16(af, bf, acc[j], 0, 0, 0);
        }
    }
#pragma unroll
    for (int j = 0; j < 8; ++j) {
        bf16x4 o;
        o[0] = f2bf(acc[j][0]); o[1] = f2bf(acc[j][1]);
        o[2] = f2bf(acc[j][2]); o[3] = f2bf(acc[j][3]);
        *(bf16x4*)(XW1T + (size_t)(j * 16 + lm) * N_ + i0 + q * 4) = o;
    }
}

// ---------------------------------------------------------------------------
// k2: ZPT[j][i] = (relu(A @ XW1) @ W2)[i][j], bf16.
// BM=16, FULL K per block (A touched as 16 linear streams, 2-KB chunks).
// TK=512 dbuf LDS for A (XOR-swizzled); B frags direct from L2, prefetch 2.
// 4 waves x 32 cols. Fused relu + @W2 epilogue.
// ---------------------------------------------------------------------------
__global__ __launch_bounds__(256) void k2_h_zp(const float* __restrict__ A,
                                               const short* __restrict__ XW1T,
                                               const float* __restrict__ W2,
                                               short* __restrict__ ZPT) {
    __shared__ short As[2][16 * 512];   // 32 KB, swizzled f(r,c)=r*512+(c^((r&7)*8))
    __shared__ short hl[16][136];
    __shared__ short w2t[32][136];
    const int tid = threadIdx.x;
    for (int idx = tid; idx < H_ * L_; idx += 256) {
        int k = idx >> 5, j = idx & 31;
        w2t[j][k] = f2bf(W2[idx]);
    }
    const int wv = tid >> 6, l = tid & 63, lm = l & 15, q = l >> 4;
    const int i0 = blockIdx.x * 16;
    // staging: 16 rows x 512 fp32; row=tid>>4, 16 thr/row, 4 rounds x 128 cols
    const int srow = tid >> 4, scol = (tid & 15) * 8;
    const int sswz = (srow & 7) * 8;
    const float* Ap = A + (size_t)(i0 + srow) * N_ + scol;
    // B: wave cols wv*32 + jt*16
    const short* Bp0 = XW1T + (size_t)(wv * 32 + lm) * N_ + q * 8;
    const short* Bp1 = XW1T + (size_t)(wv * 32 + 16 + lm) * N_ + q * 8;

    bf16x8 pb[2][2];
    pb[0][0] = *(const bf16x8*)(Bp0);      pb[0][1] = *(const bf16x8*)(Bp1);
    pb[1][0] = *(const bf16x8*)(Bp0 + 32); pb[1][1] = *(const bf16x8*)(Bp1 + 32);

    float4 sa[8];
#pragma unroll
    for (int r = 0; r < 4; ++r) {
        sa[2 * r]     = *(const float4*)(Ap + r * 128);
        sa[2 * r + 1] = *(const float4*)(Ap + r * 128 + 4);
    }
#pragma unroll
    for (int r = 0; r < 4; ++r) {
        int col = scol + r * 128;
        *(bf16x8*)&As[0][srow * 512 + (col ^ sswz)] = cvt8(sa[2 * r], sa[2 * r + 1]);
    }
#pragma unroll
    for (int r = 0; r < 4; ++r) {
        sa[2 * r]     = *(const float4*)(Ap + 512 + r * 128);
        sa[2 * r + 1] = *(const float4*)(Ap + 512 + r * 128 + 4);
    }
    __syncthreads();

    f32x4 acc[2];
    acc[0] = (f32x4){0.f, 0.f, 0.f, 0.f};
    acc[1] = (f32x4){0.f, 0.f, 0.f, 0.f};
    const int fswz = (lm & 7) * 8;
    const int NSTEP = N_ / 512;   // 16
    for (int s = 0; s < NSTEP; ++s) {
        const int b = s & 1;
#pragma unroll
        for (int m = 0; m < 16; ++m) {
            const int gm = s * 16 + m;
            const int col = m * 32 + q * 8;
            bf16x8 af = *(const bf16x8*)&As[b][lm * 512 + (col ^ fswz)];
            const int slot = gm & 1;
            bf16x8 b0 = pb[slot][0], b1 = pb[slot][1];
            pb[slot][0] = *(const bf16x8*)(Bp0 + (size_t)(gm + 2) * 32);  // overrun -> ws, safe
            pb[slot][1] = *(const bf16x8*)(Bp1 + (size_t)(gm + 2) * 32);
            acc[0] = __builtin_amdgcn_mfma_f32_16x16x32_bf16(af, b0, acc[0], 0, 0, 0);
            acc[1] = __builtin_amdgcn_mfma_f32_16x16x32_bf16(af, b1, acc[1], 0, 0, 0);
        }
        if (s + 1 < NSTEP) {
            const int nb = (s + 1) & 1;
#pragma unroll
            for (int r = 0; r < 4; ++r) {
                int col = scol + r * 128;
                *(bf16x8*)&As[nb][srow * 512 + (col ^ sswz)] = cvt8(sa[2 * r], sa[2 * r + 1]);
            }
            if (s + 2 < NSTEP) {
#pragma unroll
                for (int r = 0; r < 4; ++r) {
                    sa[2 * r]     = *(const float4*)(Ap + (size_t)(s + 2) * 512 + r * 128);
                    sa[2 * r + 1] = *(const float4*)(Ap + (size_t)(s + 2) * 512 + r * 128 + 4);
                }
            }
        }
        __syncthreads();
    }
    // relu -> hl, then h(16x128) @ W2(128x32)
#pragma unroll
    for (int jt = 0; jt < 2; ++jt)
#pragma unroll
        for (int r = 0; r < 4; ++r) {
            float v = acc[jt][r];
            hl[q * 4 + r][wv * 32 + jt * 16 + lm] = f2bf(v > 0.f ? v : 0.f);
        }
    __syncthreads();
    if (wv < 2) {
        f32x4 a2 = (f32x4){0.f, 0.f, 0.f, 0.f};
#pragma unroll
        for (int k0 = 0; k0 < H_; k0 += 32) {
            bf16x8 af2 = *(const bf16x8*)&hl[lm][k0 + q * 8];
            bf16x8 bf2 = *(const bf16x8*)&w2t[wv * 16 + lm][k0 + q * 8];
            a2 = __builtin_amdgcn_mfma_f32_16x16x32_bf16(af2, bf2, a2, 0, 0, 0);
        }
        bf16x4 o;
        o[0] = f2bf(a2[0]); o[1] = f2bf(a2[1]); o[2] = f2bf(a2[2]); o[3] = f2bf(a2[3]);
        *(bf16x4*)(ZPT + (size_t)(wv * 16 + lm) * N_ + i0 + q * 4) = o;
    }
}

// ---------------------------------------------------------------------------
// k3: Z[i][j] = (A @ ZP)[i][j], bf16 row-major. BM=32, full K (1-KB chunks),
// TK=256 dbuf LDS for A; B frags (ZPT, L2) direct with prefetch 2.
// 4 waves = 2 row-strips x 2 col-tiles.
// ---------------------------------------------------------------------------
__global__ __launch_bounds__(256) void k3_z(const float* __restrict__ A,
                                            const short* __restrict__ ZPT,
                                            short* __restrict__ Z) {
    __shared__ short As[2][32 * 256];   // 32 KB, swizzled f(r,c)=r*256+(c^((r&7)*8))
    const int tid = threadIdx.x;
    const int wv = tid >> 6, l = tid & 63, lm = l & 15, q = l >> 4;
    const int rs = (wv >> 1) & 1, jt = wv & 1;
    const int i0 = blockIdx.x * 32;
    // staging: 32 rows x 256 fp32; row=tid>>3, 8 thr/row, 4 rounds x 64 cols
    const int srow = tid >> 3, scol = (tid & 7) * 8;
    const int sswz = (srow & 7) * 8;
    const float* Ap = A + (size_t)(i0 + srow) * N_ + scol;
    const short* Bp = ZPT + (size_t)(jt * 16 + lm) * N_ + q * 8;

    bf16x8 pb[2];
    pb[0] = *(const bf16x8*)(Bp);
    pb[1] = *(const bf16x8*)(Bp + 32);

    float4 sa[8];
#pragma unroll
    for (int r = 0; r < 4; ++r) {
        sa[2 * r]     = *(const float4*)(Ap + r * 64);
        sa[2 * r + 1] = *(const float4*)(Ap + r * 64 + 4);
    }
#pragma unroll
    for (int r = 0; r < 4; ++r) {
        int col = scol + r * 64;
        *(bf16x8*)&As[0][srow * 256 + (col ^ sswz)] = cvt8(sa[2 * r], sa[2 * r + 1]);
    }
#pragma unroll
    for (int r = 0; r < 4; ++r) {
        sa[2 * r]     = *(const float4*)(Ap + 256 + r * 64);
        sa[2 * r + 1] = *(const float4*)(Ap + 256 + r * 64 + 4);
    }
    __syncthreads();

    f32x4 acc = (f32x4){0.f, 0.f, 0.f, 0.f};
    const int frow = rs * 16 + lm;
    const int fswz = (lm & 7) * 8;
    const int NSTEP = N_ / 256;   // 32
    for (int s = 0; s < NSTEP; ++s) {
        const int b = s & 1;
#pragma unroll
        for (int m = 0; m < 8; ++m) {
            const int gm = s * 8 + m;
            const int col = m * 32 + q * 8;
            bf16x8 af = *(const bf16x8*)&As[b][frow * 256 + (col ^ fswz)];
            const int slot = gm & 1;
            bf16x8 bb = pb[slot];
            pb[slot] = *(const bf16x8*)(Bp + (size_t)(gm + 2) * 32);   // overrun -> ws, safe
            acc = __builtin_amdgcn_mfma_f32_16x16x32_bf16(af, bb, acc, 0, 0, 0);
        }
        if (s + 1 < NSTEP) {
            const int nb = (s + 1) & 1;
#pragma unroll
            for (int r = 0; r < 4; ++r) {
                int col = scol + r * 64;
                *(bf16x8*)&As[nb][srow * 256 + (col ^ sswz)] = cvt8(sa[2 * r], sa[2 * r + 1]);
            }
            if (s + 2 < NSTEP) {
#pragma unroll
                for (int r = 0; r < 4; ++r) {
                    sa[2 * r]     = *(const float4*)(Ap + (size_t)(s + 2) * 256 + r * 64);
                    sa[2 * r + 1] = *(const float4*)(Ap + (size_t)(s + 2) * 256 + r * 64 + 4);
                }
            }
        }
        __syncthreads();
    }
#pragma unroll
    for (int r = 0; r < 4; ++r)
        Z[(size_t)(i0 + rs * 16 + q * 4 + r) * L_ + jt * 16 + lm] = f2bf(acc[r]);
}

// ---------------------------------------------------------------------------
// k4: out = sigmoid(Z @ Z^T). BM=16 x FULL width per block: 16 linear write
// streams, 2-KB chunks via LDS staging. Z is L2-resident; B-frag loads are
// contiguous 1-KB wave loads, prefetch 2.
// ---------------------------------------------------------------------------
__global__ __launch_bounds__(256) void k4_dec(const short* __restrict__ Z,
                                              float* __restrict__ out) {
    __shared__ float os[16][524];   // 33.5 KB
    const int tid = threadIdx.x;
    const int wv = tid >> 6, l = tid & 63;
    const int lm = l & 15, q = l >> 4;
    const int i0 = blockIdx.x * 16;
    const bf16x8 af = *(const bf16x8*)(Z + (size_t)(i0 + lm) * L_ + q * 8);
    const short* Bbase = Z + q * 8;

    bf16x8 pb[2];
    pb[0] = *(const bf16x8*)(Bbase + (size_t)(wv * 128 + lm) * L_);
    pb[1] = *(const bf16x8*)(Bbase + (size_t)(wv * 128 + 16 + lm) * L_);

    const int srow = tid >> 4, sc = (tid & 15) * 4;
    for (int rd = 0; rd < 16; ++rd) {
#pragma unroll
        for (int t = 0; t < 8; ++t) {
            const int gt = rd * 8 + t;
            const int slot = gt & 1;
            bf16x8 bb = pb[slot];
            const int nt = gt + 2;
            const int nrd = nt >> 3, ntt = nt & 7;
            pb[slot] = *(const bf16x8*)(Bbase + (size_t)(nrd * 512 + wv * 128 + ntt * 16 + lm) * L_);
            f32x4 c = __builtin_amdgcn_mfma_f32_16x16x32_bf16(
                af, bb, (f32x4){0.f, 0.f, 0.f, 0.f}, 0, 0, 0);
#pragma unroll
            for (int r = 0; r < 4; ++r) {
                float e = __expf(-c[r]);
                os[q * 4 + r][wv * 128 + t * 16 + lm] = __fdividef(1.f, 1.f + e);
            }
        }
        __syncthreads();
        {
            float* orow = out + (size_t)(i0 + srow) * N_ + rd * 512;
#pragma unroll
            for (int rr = 0; rr < 8; ++rr) {
                int col = sc + rr * 64;
                *(float4*)(orow + col) = *(const float4*)&os[srow][col];
            }
        }
        __syncthreads();
    }
}

extern "C" void kernel_launch(void* const* d_in, const int* in_sizes, int n_in,
                              void* d_out, int out_size, void* d_ws, size_t ws_size,
                              hipStream_t stream) {
    const float* X  = (const float*)d_in[0];
    const float* A  = (const float*)d_in[1];
    const float* W1 = (const float*)d_in[2];
    const float* W2 = (const float*)d_in[3];
    float* out = (float*)d_out;

    short* XW1T = (short*)d_ws;            // [H][N] bf16, 2 MB
    short* ZPT  = XW1T + (size_t)H_ * N_;  // [L][N] bf16, 512 KB
    short* Z    = ZPT + (size_t)L_ * N_;   // [N][L] bf16, 512 KB

    k1_xw1<<<N_ / 64, 256, 0, stream>>>(X, W1, XW1T);
    k2_h_zp<<<N_ / 16, 256, 0, stream>>>(A, XW1T, W2, ZPT);
    k3_z<<<N_ / 32, 256, 0, stream>>>(A, ZPT, Z);
    k4_dec<<<N_ / 16, 256, 0, stream>>>(Z, out);
}